// Round 14
// baseline (280.799 us; speedup 1.0000x reference)
//
#include <hip/hip_runtime.h>
#include <hip/hip_bf16.h>

#define BQ 4
#define HH 56
#define WW 56
#define NN (HH*WW)      // 3136
#define CC 256
#define NHEAD 8
#define HD 32
#define PP 1376
#define PPAD 1408       // 22 * 64
#define HIDN 1024
#define EPS_LN 1e-5f
// ATT_SCALE * log2(e): scores from QK^T come out ready for exp2
#define QSCALE_LOG2E 0.25503484f

typedef unsigned short bf16u;
typedef __attribute__((ext_vector_type(8))) short short8;
typedef __attribute__((ext_vector_type(4))) float f32x4;

__device__ __forceinline__ float bf2f(bf16u u){
  union { unsigned int i; float f; } v; v.i = ((unsigned int)u) << 16; return v.f;
}
__device__ __forceinline__ bf16u f2bf(float f){
  unsigned int x = __float_as_uint(f);
  x += 0x7fffu + ((x >> 16) & 1u);
  return (bf16u)(x >> 16);
}
// cheap half-up round (2 ops) for hot paths
__device__ __forceinline__ bf16u f2bf_r(float f){
  return (bf16u)((__float_as_uint(f) + 0x8000u) >> 16);
}
__device__ __forceinline__ void cvt4(const ushort4 u, float* d){
  d[0]=bf2f(u.x); d[1]=bf2f(u.y); d[2]=bf2f(u.z); d[3]=bf2f(u.w);
}

// R18: relaxed barrier -- waits only LDS ops (my ds_writes visible), does NOT
// drain vmcnt: in-flight global prefetch loads survive the barrier.
__device__ __forceinline__ void bar_lgkm(){
  asm volatile("s_waitcnt lgkmcnt(0)" ::: "memory");
  __builtin_amdgcn_s_barrier();
  asm volatile("" ::: "memory");
}

// ---------------- fused init: blocks [0,768) convert weights; rest do CPE+norm1 ----------------
// R13: CPE sliding-window row kernel; LN fused per pixel via 64-lane shfl reduce.
// R22: CPE blocks XCD-grouped (784 = 8*98) so y+-1 halo rows of x stay in one L2.
#define CSEG 4
__global__ void k_init(const float* __restrict__ qw, const float* __restrict__ kvw,
                       const float* __restrict__ pw, const float* __restrict__ f1,
                       const float* __restrict__ f2, bf16u* __restrict__ wo,
                       const float* __restrict__ x, const float* __restrict__ w,
                       const float* __restrict__ bias, const float* __restrict__ g,
                       const float* __restrict__ be, float* __restrict__ x1,
                       bf16u* __restrict__ xnb){
  if (blockIdx.x < 768){
    int off = (blockIdx.x*256 + threadIdx.x) * 4;
    const float* s;
    if (off < 65536)       s = qw  + off;
    else if (off < 196608) s = kvw + off - 65536;
    else if (off < 262144) s = pw  + off - 196608;
    else if (off < 524288) s = f1  + off - 262144;
    else                   s = f2  + off - 524288;
    float4 v = *(const float4*)s;
    ushort4 u = {f2bf(v.x), f2bf(v.y), f2bf(v.z), f2bf(v.w)};
    *(ushort4*)(wo + off) = u;
    return;
  }
  int t = threadIdx.x;
  int wave = t >> 6, lane = t & 63;
  int j = blockIdx.x - 768;                 // 784 = 8 * 98
  int jj = (j & 7) * 98 + (j >> 3);         // XCD-grouped
  int widx = jj*4 + wave;
  const int nseg = WW/CSEG;                 // 14
  int xseg = widx % nseg;
  int y    = (widx / nseg) % HH;
  int b    = widx / (nseg*HH);
  int c0 = lane*4;
  int x0 = xseg*CSEG;
  float wv[36];
  {
    const float* wp = w + (size_t)c0*9;
#pragma unroll
    for (int i = 0; i < 9; i++){
      float4 v = *(const float4*)(wp + i*4);
      wv[i*4+0]=v.x; wv[i*4+1]=v.y; wv[i*4+2]=v.z; wv[i*4+3]=v.w;
    }
  }
  float4 bi4 = *(const float4*)&bias[c0];
  float bi[4] = {bi4.x, bi4.y, bi4.z, bi4.w};
  float4 gv = *(const float4*)&g[c0];
  float4 bv = *(const float4*)&be[c0];
  const float* rowc = x + ((size_t)b*NN + (size_t)y*WW)*CC + c0;
  const float* rowm = (y > 0)    ? rowc - (size_t)WW*CC : rowc;
  const float* rowp = (y < HH-1) ? rowc + (size_t)WW*CC : rowc;
  if (y == 0){
#pragma unroll
    for (int cc = 0; cc < 4; cc++){ wv[cc*9+0]=0.f; wv[cc*9+1]=0.f; wv[cc*9+2]=0.f; }
  }
  if (y == HH-1){
#pragma unroll
    for (int cc = 0; cc < 4; cc++){ wv[cc*9+6]=0.f; wv[cc*9+7]=0.f; wv[cc*9+8]=0.f; }
  }
  float win[3][3][4];            // [col slot][row][ch]
  float4 rawA[3], rawB[3];
  if (x0 == 0){
#pragma unroll
    for (int r = 0; r < 3; r++)
#pragma unroll
      for (int cc = 0; cc < 4; cc++) win[0][r][cc] = 0.f;
  } else {
    size_t o = (size_t)(x0-1)*CC;
    float4 a0 = *(const float4*)&rowm[o];
    float4 a1 = *(const float4*)&rowc[o];
    float4 a2 = *(const float4*)&rowp[o];
    win[0][0][0]=a0.x; win[0][0][1]=a0.y; win[0][0][2]=a0.z; win[0][0][3]=a0.w;
    win[0][1][0]=a1.x; win[0][1][1]=a1.y; win[0][1][2]=a1.z; win[0][1][3]=a1.w;
    win[0][2][0]=a2.x; win[0][2][1]=a2.y; win[0][2][2]=a2.z; win[0][2][3]=a2.w;
  }
  {
    size_t o = (size_t)x0*CC;
    float4 a0 = *(const float4*)&rowm[o];
    float4 a1 = *(const float4*)&rowc[o];
    float4 a2 = *(const float4*)&rowp[o];
    win[1][0][0]=a0.x; win[1][0][1]=a0.y; win[1][0][2]=a0.z; win[1][0][3]=a0.w;
    win[1][1][0]=a1.x; win[1][1][1]=a1.y; win[1][1][2]=a1.z; win[1][1][3]=a1.w;
    win[1][2][0]=a2.x; win[1][2][1]=a2.y; win[1][2][2]=a2.z; win[1][2][3]=a2.w;
  }
  {
    size_t o = (size_t)(x0+1)*CC;      // x0+1 <= 53 < WW always
    rawA[0] = *(const float4*)&rowm[o];
    rawA[1] = *(const float4*)&rowc[o];
    rawA[2] = *(const float4*)&rowp[o];
  }
#pragma unroll
  for (int xx = 0; xx < CSEG; xx++){
    float4* cur = (xx & 1) ? rawB : rawA;
    float4* nxt = (xx & 1) ? rawA : rawB;
    if (xx < CSEG-1){
      int xg = x0 + xx + 2;
      if (xg < WW){
        size_t o = (size_t)xg*CC;
        nxt[0] = *(const float4*)&rowm[o];
        nxt[1] = *(const float4*)&rowc[o];
        nxt[2] = *(const float4*)&rowp[o];
      } else {
        float4 z = {0.f,0.f,0.f,0.f};
        nxt[0] = z; nxt[1] = z; nxt[2] = z;
      }
    }
    int sl2 = (xx+2)%3, slm = xx%3, slc = (xx+1)%3;
#pragma unroll
    for (int r = 0; r < 3; r++){
      win[sl2][r][0]=cur[r].x; win[sl2][r][1]=cur[r].y;
      win[sl2][r][2]=cur[r].z; win[sl2][r][3]=cur[r].w;
    }
    float o4[4];
#pragma unroll
    for (int cc = 0; cc < 4; cc++){
      float a = bi[cc];
      a += win[slm][0][cc]*wv[cc*9+0] + win[slc][0][cc]*wv[cc*9+1] + win[sl2][0][cc]*wv[cc*9+2];
      a += win[slm][1][cc]*wv[cc*9+3] + win[slc][1][cc]*wv[cc*9+4] + win[sl2][1][cc]*wv[cc*9+5];
      a += win[slm][2][cc]*wv[cc*9+6] + win[slc][2][cc]*wv[cc*9+7] + win[sl2][2][cc]*wv[cc*9+8];
      o4[cc] = win[slc][1][cc] + a;
    }
    size_t pix = (size_t)b*NN + (size_t)y*WW + x0 + xx;
    float4 ov = {o4[0],o4[1],o4[2],o4[3]};
    *(float4*)&x1[pix*CC + c0] = ov;
    float s  = o4[0]+o4[1]+o4[2]+o4[3];
    float s2 = o4[0]*o4[0]+o4[1]*o4[1]+o4[2]*o4[2]+o4[3]*o4[3];
#pragma unroll
    for (int off = 32; off; off >>= 1){
      s  += __shfl_xor(s,  off);
      s2 += __shfl_xor(s2, off);
    }
    float mean = s * (1.f/CC);
    float var  = s2 * (1.f/CC) - mean*mean;
    float rstd = rsqrtf(var + EPS_LN);
    float y0 = (o4[0]-mean)*rstd*gv.x + bv.x;
    float y1 = (o4[1]-mean)*rstd*gv.y + bv.y;
    float y2 = (o4[2]-mean)*rstd*gv.z + bv.z;
    float y3 = (o4[3]-mean)*rstd*gv.w + bv.w;
    ushort4 yb = {f2bf_r(y0), f2bf_r(y1), f2bf_r(y2), f2bf_r(y3)};
    *(ushort4*)&xnb[pix*CC + c0] = yb;
  }
}

// ---------------- LayerNorm f32 -> bf16 ----------------
// R15: one WAVE per row (no LDS, no barriers); lane owns 4 cols via float4.
__global__ void k_ln_bf16(const float* __restrict__ X, const float* __restrict__ g,
                          const float* __restrict__ be, bf16u* __restrict__ Y){
  int wave = threadIdx.x >> 6, lane = threadIdx.x & 63;
  int row = blockIdx.x*4 + wave;
  int c0 = lane*4;
  float4 v = *(const float4*)&X[(size_t)row*CC + c0];
  float s  = v.x+v.y+v.z+v.w;
  float s2 = v.x*v.x+v.y*v.y+v.z*v.z+v.w*v.w;
#pragma unroll
  for (int off = 32; off; off >>= 1){
    s  += __shfl_xor(s,  off);
    s2 += __shfl_xor(s2, off);
  }
  float mean = s * (1.f/CC);
  float var  = s2 * (1.f/CC) - mean*mean;
  float rstd = rsqrtf(var + EPS_LN);
  float4 gv = *(const float4*)&g[c0];
  float4 bv = *(const float4*)&be[c0];
  ushort4 yb = {f2bf_r((v.x-mean)*rstd*gv.x + bv.x),
                f2bf_r((v.y-mean)*rstd*gv.y + bv.y),
                f2bf_r((v.z-mean)*rstd*gv.z + bv.z),
                f2bf_r((v.w-mean)*rstd*gv.w + bv.w)};
  *(ushort4*)&Y[(size_t)row*CC + c0] = yb;
}

// ===== GEMM body (device): Out = act(oscale*(A @ W^T) + bias) (+Res) =====
// R12 pipelined staging; R15 depth-2 register prefetch; R18 relaxed barriers.
// R23: MT=32 tile (MW=1) -- doubles the grid for proj/fc2 (784 -> 1568 blocks,
// 3.06 -> 6.1 blocks/CU). A-chunk staging needs only 128 lanes; threads 128+
// mirror threads 0-127 (identical LDS writes, same L2 lines -- benign).
#define GST 40
template<int MT, int NT, bool OUT_BF16, bool HAS_BIAS, bool DO_GELU, bool HAS_RES, bool VT_OUT>
__device__ __forceinline__ void gemm_body(int bx, int by,
                       const bf16u* __restrict__ A, const bf16u* __restrict__ Wt,
                       const float* __restrict__ bias, void* Outp,
                       const float* Res, bf16u* __restrict__ vtout,
                       int Nout, int K, float oscale,
                       bf16u* __restrict__ AshB, bf16u* __restrict__ BshB){
  constexpr int MW = (MT == 128) ? 4 : ((MT == 64) ? 2 : 1);
  constexpr int NW = (NT == 128) ? 4 : 2;
  bf16u* Ash0 = AshB; bf16u* Ash1 = AshB + MT*GST;
  bf16u* Bsh0 = BshB; bf16u* Bsh1 = BshB + NT*GST;
  int t = threadIdx.x;
  int wave = t >> 6, lane = t & 63, quad = lane >> 4, l16 = lane & 15;
  int m0 = by * MT, n0 = bx * NT;
  int wm = (wave >> 1) * (MT/2);
  int wn = (wave & 1) * (NT/2);
  int ar = (MT==128) ? (t>>1) : ((MT==64) ? (t>>2) : ((t&127)>>2));
  int ac = (MT==128) ? ((t&1)*16) : ((t&3)*8);
  int br = (NT==128) ? (t>>1) : (t>>2);
  int bc = (NT==128) ? ((t&1)*16) : ((t&3)*8);
  int astore = ar*GST + ac;
  int bstore = br*GST + bc;
  const bf16u* ap = A  + (size_t)(m0+ar)*K + ac;
  const bf16u* bp = Wt + (size_t)(n0+br)*K + bc;

  // prologue: stage chunk 0 directly; prefetch chunk 1 -> setA, chunk 2 -> setB
  {
    uint4 t0 = *(const uint4*)ap;
    *(uint4*)&Ash0[astore] = t0;
    if constexpr (MT == 128){ uint4 t1 = *(const uint4*)(ap+8); *(uint4*)&Ash0[astore+8] = t1; }
    uint4 t2 = *(const uint4*)bp;
    *(uint4*)&Bsh0[bstore] = t2;
    if constexpr (NT == 128){ uint4 t3 = *(const uint4*)(bp+8); *(uint4*)&Bsh0[bstore+8] = t3; }
  }
  uint4 aA0, aA1, bA0, bA1;   // setA (odd chunks)
  uint4 aB0, aB1, bB0, bB1;   // setB (even chunks)
  ap += 32; bp += 32;
  aA0 = *(const uint4*)ap;
  if constexpr (MT == 128) aA1 = *(const uint4*)(ap+8);
  bA0 = *(const uint4*)bp;
  if constexpr (NT == 128) bA1 = *(const uint4*)(bp+8);
  ap += 32; bp += 32;
  aB0 = *(const uint4*)ap;
  if constexpr (MT == 128) aB1 = *(const uint4*)(ap+8);
  bB0 = *(const uint4*)bp;
  if constexpr (NT == 128) bB1 = *(const uint4*)(bp+8);
  ap += 32; bp += 32;        // -> chunk 3
  bar_lgkm();

  f32x4 zero = {0.f,0.f,0.f,0.f};
  f32x4 acc[MW][NW];
#pragma unroll
  for (int i = 0; i < MW; i++)
#pragma unroll
    for (int j = 0; j < NW; j++) acc[i][j] = zero;

  int nks = K >> 5;

#define GEMM_STEP(AshP, BshP) { \
    short8 af[MW], bfr[NW]; \
    _Pragma("unroll") \
    for (int mi = 0; mi < MW; mi++) \
      af[mi] = *(const short8*)&AshP[(wm + mi*16 + l16)*GST + quad*8]; \
    _Pragma("unroll") \
    for (int ni = 0; ni < NW; ni++) \
      bfr[ni] = *(const short8*)&BshP[(wn + ni*16 + l16)*GST + quad*8]; \
    _Pragma("unroll") \
    for (int mi = 0; mi < MW; mi++) \
      _Pragma("unroll") \
      for (int ni = 0; ni < NW; ni++) \
        acc[mi][ni] = __builtin_amdgcn_mfma_f32_16x16x32_bf16(af[mi], bfr[ni], acc[mi][ni], 0,0,0); }

  for (int ks = 0; ks < nks; ks += 2){
    // even sub-iter: compute buf0; store setA (chunk ks+1) -> buf1; reload setA <- chunk ks+3
    if (ks < nks-1){
      *(uint4*)&Ash1[astore] = aA0;
      if constexpr (MT == 128) *(uint4*)&Ash1[astore+8] = aA1;
      *(uint4*)&Bsh1[bstore] = bA0;
      if constexpr (NT == 128) *(uint4*)&Bsh1[bstore+8] = bA1;
      if (ks < nks-3){
        aA0 = *(const uint4*)ap;
        if constexpr (MT == 128) aA1 = *(const uint4*)(ap+8);
        bA0 = *(const uint4*)bp;
        if constexpr (NT == 128) bA1 = *(const uint4*)(bp+8);
        ap += 32; bp += 32;
      }
    }
    GEMM_STEP(Ash0, Bsh0)
    if (ks < nks-1) bar_lgkm();
    // odd sub-iter: compute buf1; store setB (chunk ks+2) -> buf0; reload setB <- chunk ks+4
    if (ks+1 < nks-1){
      *(uint4*)&Ash0[astore] = aB0;
      if constexpr (MT == 128) *(uint4*)&Ash0[astore+8] = aB1;
      *(uint4*)&Bsh0[bstore] = bB0;
      if constexpr (NT == 128) *(uint4*)&Bsh0[bstore+8] = bB1;
      if (ks+1 < nks-3){
        aB0 = *(const uint4*)ap;
        if constexpr (MT == 128) aB1 = *(const uint4*)(ap+8);
        bB0 = *(const uint4*)bp;
        if constexpr (NT == 128) bB1 = *(const uint4*)(bp+8);
        ap += 32; bp += 32;
      }
    }
    if (ks+1 < nks){
      GEMM_STEP(Ash1, Bsh1)
      if (ks+1 < nks-1) bar_lgkm();
    }
  }
#undef GEMM_STEP

#pragma unroll
  for (int mi = 0; mi < MW; mi++){
#pragma unroll
    for (int r = 0; r < 4; r++){
      int row = m0 + wm + mi*16 + quad*4 + r;
#pragma unroll
      for (int ni = 0; ni < NW; ni++){
        int col = n0 + wn + ni*16 + l16;
        float v = acc[mi][ni][r] * oscale;
        if constexpr (HAS_BIAS) v += bias[col];
        if constexpr (DO_GELU)  v = 0.5f*v*(1.f + erff(v*0.70710678118654752f));
        if constexpr (HAS_RES)  v += Res[(size_t)row*Nout + col];
        if constexpr (VT_OUT){
          if (col < CC){
            ((bf16u*)Outp)[(size_t)row*Nout + col] = f2bf_r(v);
          } else {
            int bb = row / PP, pp = row - bb*PP;
            vtout[((size_t)(bb*CC + (col - CC)))*PPAD + pp] = f2bf_r(v);
          }
        } else if constexpr (OUT_BF16){
          ((bf16u*)Outp)[(size_t)row*Nout + col] = f2bf_r(v);
        } else {
          ((float*)Outp)[(size_t)row*Nout + col] = v;
        }
      }
    }
  }
}

// R18: 1-D grid + bijective XCD swizzle (nwg % 8 == 0 at every call site).
template<int MT, int NT, bool OUT_BF16, bool HAS_BIAS, bool DO_GELU, bool HAS_RES, bool VT_OUT>
__global__ __launch_bounds__(256) void k_gemm_mfma(const bf16u* __restrict__ A,
                       const bf16u* __restrict__ Wt,
                       const float* __restrict__ bias, void* Outp,
                       const float* Res, bf16u* __restrict__ vtout,
                       int NX, int Nout, int K, float oscale){
  __shared__ bf16u Ash[2][MT*GST];
  __shared__ bf16u Bsh[2][NT*GST];
  int i = blockIdx.x;
  int w = (i & 7) * ((int)gridDim.x >> 3) + (i >> 3);
  int bx = w % NX, by = w / NX;
  gemm_body<MT,NT,OUT_BF16,HAS_BIAS,DO_GELU,HAS_RES,VT_OUT>(
      bx, by, A, Wt, bias, Outp, Res, vtout, Nout, K, oscale,
      &Ash[0][0], &Bsh[0][0]);
}

// ---------------- R17 fused: q-projection GEMM + adaptive avg pool ----------------
#define QGRID ((CC/64)*(BQ*NN/64))    // 4*196 = 784
__global__ __launch_bounds__(256) void k_qpool(const bf16u* __restrict__ xnb,
                       const bf16u* __restrict__ wq, bf16u* __restrict__ qb,
                       float* __restrict__ praw){
  __shared__ bf16u Ash[2][64*GST];
  __shared__ bf16u Bsh[2][64*GST];
  if (blockIdx.x < QGRID){
    int i = blockIdx.x;
    int w = (i & 7) * (QGRID >> 3) + (i >> 3);   // XCD swizzle within q part
    int bx = w & 3, by = w >> 2;
    gemm_body<64,64,true,false,false,false,false>(
        bx, by, xnb, wq, nullptr, qb, nullptr, nullptr, CC, CC, QSCALE_LOG2E,
        &Ash[0][0], &Bsh[0][0]);
    return;
  }
  // pool path: one wave per pool pixel, lane owns 4 channels
  int wave = threadIdx.x >> 6, lane = threadIdx.x & 63;
  int bp = (blockIdx.x - QGRID)*4 + wave;
  int b = bp / PP, p = bp % PP;
  int ps, pi;
  if (p < 144)      { ps = 12; pi = p; }
  else if (p < 400) { ps = 16; pi = p - 144; }
  else if (p < 800) { ps = 20; pi = p - 400; }
  else              { ps = 24; pi = p - 800; }
  int oi = pi / ps, oj = pi % ps;
  int si = oi*HH/ps, ei = ((oi+1)*HH + ps - 1)/ps;
  int sj = oj*WW/ps, ej = ((oj+1)*WW + ps - 1)/ps;
  int c0 = lane*4;
  const bf16u* xb = xnb + (size_t)b*NN*CC + c0;
  float a0=0.f, a1=0.f, a2=0.f, a3=0.f;
  for (int i = si; i < ei; i++)
    for (int j = sj; j < ej; j++){
      ushort4 v = *(const ushort4*)&xb[(size_t)(i*WW+j)*CC];
      a0 += bf2f(v.x); a1 += bf2f(v.y); a2 += bf2f(v.z); a3 += bf2f(v.w);
    }
  float inv = 1.f / (float)((ei-si)*(ej-sj));
  float4 o = {a0*inv, a1*inv, a2*inv, a3*inv};
  *(float4*)&praw[(size_t)bp*CC + c0] = o;
}

// ---------------- pool-dwconv + attn-norm fused -> bf16 ----------------
// R21: one WAVE per pool pixel (4/block), lane owns 4 channels via float4.
__global__ __launch_bounds__(256) void k_pooldw_ln(const float* __restrict__ praw,
    const float* w0, const float* b0, const float* w1, const float* b1,
    const float* w2, const float* b2, const float* w3, const float* b3,
    const float* __restrict__ g, const float* __restrict__ be,
    bf16u* __restrict__ pools){
  int wave = threadIdx.x >> 6, lane = threadIdx.x & 63;
  int bp = blockIdx.x*4 + wave;
  int b = bp / PP, p = bp % PP;
  int ps, pi, off; const float *w, *bi;
  if (p < 144)      { ps=12; pi=p;     off=0;   w=w0; bi=b0; }
  else if (p < 400) { ps=16; pi=p-144; off=144; w=w1; bi=b1; }
  else if (p < 800) { ps=20; pi=p-400; off=400; w=w2; bi=b2; }
  else              { ps=24; pi=p-800; off=800; w=w3; bi=b3; }
  int oi = pi/ps, oj = pi%ps;
  int c0 = lane*4;
  const float* base = praw + (size_t)(b*PP + off)*CC + c0;
  // weights for 4 channels (dwconv layout [C][9] -> per-channel scalar loads)
  float wv[36];
#pragma unroll
  for (int cc = 0; cc < 4; cc++)
#pragma unroll
    for (int k = 0; k < 9; k++) wv[cc*9+k] = w[(size_t)(c0+cc)*9 + k];
  float4 bi4 = *(const float4*)&bi[c0];
  float acc[4] = {bi4.x, bi4.y, bi4.z, bi4.w};
#pragma unroll
  for (int kh = 0; kh < 3; kh++){
    int ii = oi + kh - 1; if (ii < 0 || ii >= ps) continue;
#pragma unroll
    for (int kw = 0; kw < 3; kw++){
      int jj = oj + kw - 1; if (jj < 0 || jj >= ps) continue;
      float4 v = *(const float4*)&base[(size_t)(ii*ps+jj)*CC];
      int k = kh*3+kw;
      acc[0] += v.x*wv[0*9+k]; acc[1] += v.y*wv[1*9+k];
      acc[2] += v.z*wv[2*9+k]; acc[3] += v.w*wv[3*9+k];
    }
  }
  float4 ctr = *(const float4*)&base[(size_t)(oi*ps+oj)*CC];
  float v0 = ctr.x + acc[0], v1 = ctr.y + acc[1];
  float v2 = ctr.z + acc[2], v3 = ctr.w + acc[3];
  float s  = v0+v1+v2+v3;
  float s2 = v0*v0+v1*v1+v2*v2+v3*v3;
#pragma unroll
  for (int o2_ = 32; o2_; o2_ >>= 1){
    s  += __shfl_xor(s,  o2_);
    s2 += __shfl_xor(s2, o2_);
  }
  float mean = s * (1.f/CC);
  float var  = s2 * (1.f/CC) - mean*mean;
  float rstd = rsqrtf(var + EPS_LN);
  float4 gv = *(const float4*)&g[c0];
  float4 bv = *(const float4*)&be[c0];
  ushort4 yb = {f2bf_r((v0-mean)*rstd*gv.x + bv.x),
                f2bf_r((v1-mean)*rstd*gv.y + bv.y),
                f2bf_r((v2-mean)*rstd*gv.z + bv.z),
                f2bf_r((v3-mean)*rstd*gv.w + bv.w)};
  *(ushort4*)&pools[(size_t)bp*CC + c0] = yb;
}

// ============ MFMA flash attention: 64 q x 1 head per block, 64-key chunks ============
// R14 layout (sigma store permute, linear frag reads, KST=40). R15 VALU cuts
// (ones-MFMA rowsum, perm-pack). R18 relaxed barriers + XCD grouping.
// R19: DEPTH-2 K/V register prefetch (statically 2x-unrolled chunk loop).
#define KST 40   // 32 dims + 8 pad
#define VST 72   // 64 keys + 8 pad
__global__ __launch_bounds__(256) void k_attn_mfma(const bf16u* __restrict__ q,
                       const bf16u* __restrict__ kvb, const bf16u* __restrict__ vt,
                       bf16u* __restrict__ out){
  __shared__ bf16u Ksh[2][64*KST];     // [buf][sigma(key)][32 dims]
  __shared__ bf16u Vsh[2][32*VST];     // [buf][d][64 keys]
  int t = threadIdx.x;
  int wave = t >> 6, lane = t & 63, quad = lane >> 4, l16 = lane & 15;
  int i = blockIdx.x;                      // 1568 = 8 * 196
  int bid = (i & 7) * 196 + (i >> 3);      // 49-block (b,h) groups stay on one XCD
  int qt = bid % (NN/64);
  int h  = (bid / (NN/64)) % NHEAD;
  int b  = bid / ((NN/64)*NHEAD);
  int q0 = qt*64 + wave*16;
  const bf16u* qptr = q + (size_t)(b*NN + q0 + l16)*CC + h*HD + quad*8;
  short8 qf = *(const short8*)qptr;
  f32x4 zero = {0.f,0.f,0.f,0.f};
  f32x4 o0 = zero, o1 = zero, osum = zero;
  const short8 onesf = {0x3F80,0x3F80,0x3F80,0x3F80,0x3F80,0x3F80,0x3F80,0x3F80};
  // staging: K chunk = 64 rows x 64B (4 thr/row), V chunk = 32 rows x 128B (8 thr/row)
  int ksr = t >> 2, ksc = (t & 3) * 8;
  int vsr = t >> 3, vsc = (t & 7) * 8;
  const bf16u* ksrc = kvb + (size_t)(b*PP + ksr)*(2*CC) + h*HD + ksc;
  const bf16u* vsrc = vt  + (size_t)(b*CC + h*HD + vsr)*PPAD + vsc;
  const size_t KSTEP = (size_t)64*(2*CC);
  // sigma(key): bit5=k5, bit4=k2, bits3:2=k4:3, bits1:0=k1:0 (pure bit permutation)
  int krow = (ksr & 32) | ((ksr & 4) << 2) | ((ksr & 24) >> 1) | (ksr & 3);
  int kstore = krow*KST + ksc;
  int vstore = vsr*VST + vsc;
  // linear fragment reads (conflict-free at stride 40)
  int koffA = l16*KST + quad*8;
  int koffB = koffA + 16*KST;
  int voff0 = l16*VST + quad*8;
  int voff1 = (16 + l16)*VST + quad*8;
  bf16u* Ksh0 = &Ksh[0][0]; bf16u* Ksh1 = &Ksh[1][0];
  bf16u* Vsh0 = &Vsh[0][0]; bf16u* Vsh1 = &Vsh[1][0];

  // prologue: stage chunk 0 -> buf0; load chunk 1 -> setA; chunk 2 -> setB
  {
    uint4 k0 = *(const uint4*)ksrc;
    uint4 v0 = *(const uint4*)vsrc;
    *(uint4*)&Ksh0[kstore] = k0;
    *(uint4*)&Vsh0[vstore] = v0;
  }
  uint4 kA, vA, kB, vB;
  ksrc += KSTEP; vsrc += 64;
  kA = *(const uint4*)ksrc; vA = *(const uint4*)vsrc;
  ksrc += KSTEP; vsrc += 64;
  kB = *(const uint4*)ksrc; vB = *(const uint4*)vsrc;
  ksrc += KSTEP; vsrc += 64;       // -> chunk 3
  bar_lgkm();

#define PAIR(KB_, VB_, cb) { \
    short8 kfa = *(const short8*)&KB_[cb*KST + koffA]; \
    short8 kfb = *(const short8*)&KB_[cb*KST + koffB]; \
    f32x4 sa = __builtin_amdgcn_mfma_f32_16x16x32_bf16(kfa, qf, zero, 0,0,0); \
    f32x4 sb = __builtin_amdgcn_mfma_f32_16x16x32_bf16(kfb, qf, zero, 0,0,0); \
    float ea0 = __builtin_amdgcn_exp2f(sa[0]), ea1 = __builtin_amdgcn_exp2f(sa[1]); \
    float ea2 = __builtin_amdgcn_exp2f(sa[2]), ea3 = __builtin_amdgcn_exp2f(sa[3]); \
    float eb0 = __builtin_amdgcn_exp2f(sb[0]), eb1 = __builtin_amdgcn_exp2f(sb[1]); \
    float eb2 = __builtin_amdgcn_exp2f(sb[2]), eb3 = __builtin_amdgcn_exp2f(sb[3]); \
    unsigned ra0 = __float_as_uint(ea0) + 0x8000u, ra1 = __float_as_uint(ea1) + 0x8000u; \
    unsigned ra2 = __float_as_uint(ea2) + 0x8000u, ra3 = __float_as_uint(ea3) + 0x8000u; \
    unsigned rb0 = __float_as_uint(eb0) + 0x8000u, rb1 = __float_as_uint(eb1) + 0x8000u; \
    unsigned rb2 = __float_as_uint(eb2) + 0x8000u, rb3 = __float_as_uint(eb3) + 0x8000u; \
    union { uint4 u; short8 s; } pk; \
    pk.u.x = __builtin_amdgcn_perm(ra1, ra0, 0x07060302u); \
    pk.u.y = __builtin_amdgcn_perm(ra3, ra2, 0x07060302u); \
    pk.u.z = __builtin_amdgcn_perm(rb1, rb0, 0x07060302u); \
    pk.u.w = __builtin_amdgcn_perm(rb3, rb2, 0x07060302u); \
    short8 pa = pk.s; \
    short8 vf0 = *(const short8*)&VB_[cb + voff0]; \
    short8 vf1 = *(const short8*)&VB_[cb + voff1]; \
    o0 = __builtin_amdgcn_mfma_f32_16x16x32_bf16(pa, vf0, o0, 0,0,0); \
    o1 = __builtin_amdgcn_mfma_f32_16x16x32_bf16(pa, vf1, o1, 0,0,0); \
    osum = __builtin_amdgcn_mfma_f32_16x16x32_bf16(pa, onesf, osum, 0,0,0); }

  // chunks 0..20 processed in iters 0..20; chunk c lives in buf c&1.
  for (int ch = 0; ch < 20; ch += 2){
    // even iter ch: read buf0, store setA (chunk ch+1) -> buf1
    *(uint4*)&Ksh1[kstore] = kA;
    *(uint4*)&Vsh1[vstore] = vA;
    kA = *(const uint4*)ksrc; vA = *(const uint4*)vsrc;   // chunk ch+3
    ksrc += KSTEP; vsrc += 64;
    PAIR(Ksh0, Vsh0, 0)
    PAIR(Ksh0, Vsh0, 32)
    bar_lgkm();
    // odd iter ch+1: read buf1, store setB (chunk ch+2) -> buf0
    *(uint4*)&Ksh0[kstore] = kB;
    *(uint4*)&Vsh0[vstore] = vB;
    if (ch+1 <= 17){                                      // chunk ch+4 valid (<=21)
      kB = *(const uint4*)ksrc; vB = *(const uint4*)vsrc;
      ksrc += KSTEP; vsrc += 64;
    }
    PAIR(Ksh1, Vsh1, 0)
    PAIR(Ksh1, Vsh1, 32)
    bar_lgkm();
  }
  // iter 20 (even): store setA (chunk 21) -> buf1; no further loads
  *(uint4*)&Ksh1[kstore] = kA;
  *(uint4*)&Vsh1[vstore] = vA;
  PAIR(Ksh0, Vsh0, 0)
  PAIR(Ksh0, Vsh0, 32)
  bar_lgkm();
  // tail chunk 21 (buf1): keys 1344..1375 valid, 1376..1407 masked off entirely
  PAIR(Ksh1, Vsh1, 0)
#undef PAIR

  // osum[r] = sum of P over all keys for q-row quad*4+r -- exactly the row this
  // lane writes; no shuffles needed.
#pragma unroll
  for (int r = 0; r < 4; r++){
    int qq = quad*4 + r;
    float inv = 1.f / osum[r];
    size_t base = (size_t)(b*NN + q0 + qq)*CC + h*HD;
    out[base + l16]      = f2bf_r(o0[r]*inv);
    out[base + 16 + l16] = f2bf_r(o1[r]*inv);
  }
}

// ---------------- h2 = h + dwconv3x3(h) + bias (hid=1024, bf16) ----------------
// R11: sliding-window row kernel. R22: XCD-grouped bid (1568 = 8*196) so blocks
// sharing y+-1 halo rows of hbuf hit one L2.
#define DWSEG 8
__global__ __launch_bounds__(256) void k_dwh(const bf16u* __restrict__ h, const float* __restrict__ w,
                      const float* __restrict__ bias, bf16u* __restrict__ h2){
  const int nseg = WW/DWSEG;     // 7
  int i = blockIdx.x;            // 1568 = 8 * 196
  int bid = (i & 7) * 196 + (i >> 3);
  int xseg = bid % nseg;
  int y    = (bid / nseg) % HH;
  int b    = bid / (nseg*HH);
  int t = threadIdx.x;
  int c0 = t*4;
  int x0 = xseg*DWSEG;
  float wv[36];
  {
    const float4* wp = (const float4*)(w + (size_t)c0*9);
#pragma unroll
    for (int i2 = 0; i2 < 9; i2++){
      float4 v = wp[i2];
      wv[i2*4+0]=v.x; wv[i2*4+1]=v.y; wv[i2*4+2]=v.z; wv[i2*4+3]=v.w;
    }
  }
  float4 bi4 = *(const float4*)&bias[c0];
  float bi[4] = {bi4.x, bi4.y, bi4.z, bi4.w};
  const bf16u* rowc = h + ((size_t)b*NN + (size_t)y*WW)*HIDN + c0;
  const bf16u* rowm = (y > 0)    ? rowc - (size_t)WW*HIDN : rowc;
  const bf16u* rowp = (y < HH-1) ? rowc + (size_t)WW*HIDN : rowc;
  if (y == 0){
#pragma unroll
    for (int cc = 0; cc < 4; cc++){ wv[cc*9+0]=0.f; wv[cc*9+1]=0.f; wv[cc*9+2]=0.f; }
  }
  if (y == HH-1){
#pragma unroll
    for (int cc = 0; cc < 4; cc++){ wv[cc*9+6]=0.f; wv[cc*9+7]=0.f; wv[cc*9+8]=0.f; }
  }
  float win[3][3][4];            // [col slot][row][ch]
  ushort4 rawA[3], rawB[3];
  if (x0 == 0){
#pragma unroll
    for (int r = 0; r < 3; r++)
#pragma unroll
      for (int cc = 0; cc < 4; cc++) win[0][r][cc] = 0.f;
  } else {
    size_t o = (size_t)(x0-1)*HIDN;
    ushort4 a0 = *(const ushort4*)&rowm[o];
    ushort4 a1 = *(const ushort4*)&rowc[o];
    ushort4 a2 = *(const ushort4*)&rowp[o];
    cvt4(a0, win[0][0]); cvt4(a1, win[0][1]); cvt4(a2, win[0][2]);
  }
  {
    size_t o = (size_t)x0*HIDN;
    ushort4 a0 = *(const ushort4*)&rowm[o];
    ushort4 a1 = *(const ushort4*)&rowc[o];
    ushort4 a2 = *(const ushort4*)&rowp[o];
    cvt4(a0, win[1][0]); cvt4(a1, win[1][1]); cvt4(a2, win[1][2]);
  }
  {
    size_t o = (size_t)(x0+1)*HIDN;
    rawA[0] = *(const ushort4*)&rowm[o];
    rawA[1] = *(const ushort4*)&rowc[o];
    rawA[2] = *(const ushort4*)&rowp[o];
  }
#pragma unroll
  for (int x = 0; x < DWSEG; x++){
    ushort4* cur = (x & 1) ? rawB : rawA;
    ushort4* nxt = (x & 1) ? rawA : rawB;
    if (x < DWSEG-1){
      int xg = x0 + x + 2;
      if (xg < WW){
        size_t o = (size_t)xg*HIDN;
        nxt[0] = *(const ushort4*)&rowm[o];
        nxt[1] = *(const ushort4*)&rowc[o];
        nxt[2] = *(const ushort4*)&rowp[o];
      } else {
        ushort4 z = {0,0,0,0};
        nxt[0] = z; nxt[1] = z; nxt[2] = z;
      }
    }
    int s2 = (x+2)%3, sm = x%3, sc_ = (x+1)%3;
    cvt4(cur[0], win[s2][0]); cvt4(cur[1], win[s2][1]); cvt4(cur[2], win[s2][2]);
    float o0[4];
#pragma unroll
    for (int cc = 0; cc < 4; cc++){
      float a = bi[cc];
      a += win[sm][0][cc]*wv[cc*9+0] + win[sc_][0][cc]*wv[cc*9+1] + win[s2][0][cc]*wv[cc*9+2];
      a += win[sm][1][cc]*wv[cc*9+3] + win[sc_][1][cc]*wv[cc*9+4] + win[s2][1][cc]*wv[cc*9+5];
      a += win[sm][2][cc]*wv[cc*9+6] + win[sc_][2][cc]*wv[cc*9+7] + win[s2][2][cc]*wv[cc*9+8];
      o0[cc] = win[sc_][1][cc] + a;
    }
    ushort4 ou = {f2bf_r(o0[0]), f2bf_r(o0[1]), f2bf_r(o0[2]), f2bf_r(o0[3])};
    *(ushort4*)&h2[((size_t)b*NN + (size_t)y*WW + x0 + x)*HIDN + c0] = ou;
  }
}

extern "C" void kernel_launch(void* const* d_in, const int* in_sizes, int n_in,
                              void* d_out, int out_size, void* d_ws, size_t ws_size,
                              hipStream_t stream){
  const float* x      = (const float*)d_in[0];
  const float* cpe_w  = (const float*)d_in[1];
  const float* cpe_b  = (const float*)d_in[2];
  const float* n1w    = (const float*)d_in[3];
  const float* n1b    = (const float*)d_in[4];
  const float* q_w    = (const float*)d_in[5];
  const float* kv_w   = (const float*)d_in[6];
  const float* anw    = (const float*)d_in[7];
  const float* anb    = (const float*)d_in[8];
  const float* proj_w = (const float*)d_in[9];
  const float* proj_b = (const float*)d_in[10];
  const float* n2w    = (const float*)d_in[11];
  const float* n2b    = (const float*)d_in[12];
  const float* fc1_w  = (const float*)d_in[13];
  const float* fc1_b  = (const float*)d_in[14];
  const float* irb_w  = (const float*)d_in[15];
  const float* irb_b  = (const float*)d_in[16];
  const float* fc2_w  = (const float*)d_in[17];
  const float* fc2_b  = (const float*)d_in[18];
  const float* dw0    = (const float*)d_in[21];
  const float* db0    = (const float*)d_in[22];
  const float* dw1    = (const float*)d_in[23];
  const float* db1    = (const float*)d_in[24];
  const float* dw2    = (const float*)d_in[25];
  const float* db2    = (const float*)d_in[26];
  const float* dw3    = (const float*)d_in[27];
  const float* db3    = (const float*)d_in[28];

  const size_t BNC = (size_t)BQ*NN*CC;
  const size_t BPC = (size_t)BQ*PP*CC;
  const size_t BNH = (size_t)BQ*NN*HIDN;

  float* x1   = (float*)d_ws;
  bf16u* xnb  = (bf16u*)(x1 + BNC);
  bf16u* wbuf = xnb + BNC;
  bf16u* wq   = wbuf;
  bf16u* wkv  = wbuf + 65536;
  bf16u* wpj  = wbuf + 196608;
  bf16u* wf1  = wbuf + 262144;
  bf16u* wf2  = wbuf + 524288;
  float* A0   = (float*)(wbuf + 786432);
  bf16u* qb   = (bf16u*)A0;
  float* praw = (float*)(qb + BNC);
  bf16u* poolsb = (bf16u*)(praw + BPC);
  bf16u* kvb  = poolsb + BPC;                 // [BQ*PP][512] (V-half unused by attn)
  bf16u* vtb  = kvb + (size_t)BQ*PP*2*CC;     // [BQ*256][PPAD]
  bf16u* hbuf = (bf16u*)A0;                   // phase-2 overlay (qb dead after proj)
  bf16u* h2buf = hbuf + BNH;

  // 1. weights->bf16 (768 blocks) + CPE+residual+norm1 (784 blocks, XCD-grouped)
  k_init<<<768 + (BQ*HH*(WW/CSEG))/4, 256, 0, stream>>>(q_w, kv_w, proj_w, fc1_w, fc2_w, wbuf,
                                            x, cpe_w, cpe_b, n1w, n1b, x1, xnb);
  // 2+3. fused q projection (784 blocks, XCD-swizzled) + pyramid pooling (1376 blocks)
  k_qpool<<<QGRID + BQ*PP/4, 256, 0, stream>>>(xnb, wq, qb, praw);
  // 4. pool dwconv + attn-norm -> bf16 (1 wave/pixel, float4)
  k_pooldw_ln<<<BQ*PP/4, 256, 0, stream>>>(praw, dw0,db0, dw1,db1, dw2,db2, dw3,db3,
                                           anw, anb, poolsb);
  // 5. kv projection -> bf16, 64x64 tiles (688 blocks, NX=8); V-half -> vtb
  k_gemm_mfma<64,64,true,false,false,false,true><<<(2*CC/64)*(BQ*PP/64), 256, 0, stream>>>(
      poolsb, wkv, nullptr, kvb, nullptr, vtb, 2*CC/64, 2*CC, CC, 1.0f);
  // 6. MFMA attention (in-place: qb becomes attn output); depth-2 prefetch
  k_attn_mfma<<<BQ*NHEAD*(NN/64), 256, 0, stream>>>(qb, kvb, vtb, qb);
  // 7. proj + bias + residual -> x1, R23: 32x64 tiles (1568 blocks, NX=4)
  k_gemm_mfma<32,64,false,true,false,true,false><<<(CC/64)*(BQ*NN/32), 256, 0, stream>>>(
      qb, wpj, proj_b, x1, x1, nullptr, CC/64, CC, CC, 1.0f);
  // 8. norm2 -> bf16 (1 wave/row)
  k_ln_bf16<<<BQ*NN/4, 256, 0, stream>>>(x1, n2w, n2b, xnb);
  // 9. fc1 + bias + gelu -> hbuf (bf16), 64x64 tiles (3136 blocks, NX=16)
  k_gemm_mfma<64,64,true,true,true,false,false><<<(HIDN/64)*(BQ*NN/64), 256, 0, stream>>>(
      xnb, wf1, fc1_b, hbuf, nullptr, nullptr, HIDN/64, HIDN, CC, 1.0f);
  // 10. h2 = h + dwconv(h), sliding-window row kernel (XCD-grouped)
  k_dwh<<<BQ*HH*(WW/DWSEG), 256, 0, stream>>>(hbuf, irb_w, irb_b, h2buf);
  // 11. fc2 + bias + residual -> d_out (f32), R23: 32x64 tiles (1568 blocks, NX=4)
  k_gemm_mfma<32,64,false,true,false,true,false><<<(CC/64)*(BQ*NN/32), 256, 0, stream>>>(
      h2buf, wf2, fc2_b, d_out, x1, nullptr, CC/64, CC, HIDN, 1.0f);
}

// Round 15
// 272.398 us; speedup vs baseline: 1.0308x; 1.0308x over previous
//
#include <hip/hip_runtime.h>
#include <hip/hip_bf16.h>

#define BQ 4
#define HH 56
#define WW 56
#define NN (HH*WW)      // 3136
#define CC 256
#define NHEAD 8
#define HD 32
#define PP 1376
#define PPAD 1408       // 22 * 64
#define HIDN 1024
#define EPS_LN 1e-5f
// ATT_SCALE * log2(e): scores from QK^T come out ready for exp2
#define QSCALE_LOG2E 0.25503484f

typedef unsigned short bf16u;
typedef __attribute__((ext_vector_type(8))) short short8;
typedef __attribute__((ext_vector_type(4))) float f32x4;

__device__ __forceinline__ float bf2f(bf16u u){
  union { unsigned int i; float f; } v; v.i = ((unsigned int)u) << 16; return v.f;
}
__device__ __forceinline__ bf16u f2bf(float f){
  unsigned int x = __float_as_uint(f);
  x += 0x7fffu + ((x >> 16) & 1u);
  return (bf16u)(x >> 16);
}
// cheap half-up round (2 ops) for hot paths
__device__ __forceinline__ bf16u f2bf_r(float f){
  return (bf16u)((__float_as_uint(f) + 0x8000u) >> 16);
}
__device__ __forceinline__ void cvt4(const ushort4 u, float* d){
  d[0]=bf2f(u.x); d[1]=bf2f(u.y); d[2]=bf2f(u.z); d[3]=bf2f(u.w);
}

// R18: relaxed barrier -- waits only LDS ops (my ds_writes visible), does NOT
// drain vmcnt: in-flight global prefetch loads survive the barrier.
__device__ __forceinline__ void bar_lgkm(){
  asm volatile("s_waitcnt lgkmcnt(0)" ::: "memory");
  __builtin_amdgcn_s_barrier();
  asm volatile("" ::: "memory");
}

// ---------------- fused init: blocks [0,768) convert weights; rest do CPE+norm1 ----------------
// R13: CPE sliding-window row kernel; LN fused per pixel via 64-lane shfl reduce.
// R22: CPE blocks XCD-grouped (784 = 8*98) so y+-1 halo rows of x stay in one L2.
#define CSEG 4
__global__ void k_init(const float* __restrict__ qw, const float* __restrict__ kvw,
                       const float* __restrict__ pw, const float* __restrict__ f1,
                       const float* __restrict__ f2, bf16u* __restrict__ wo,
                       const float* __restrict__ x, const float* __restrict__ w,
                       const float* __restrict__ bias, const float* __restrict__ g,
                       const float* __restrict__ be, float* __restrict__ x1,
                       bf16u* __restrict__ xnb){
  if (blockIdx.x < 768){
    int off = (blockIdx.x*256 + threadIdx.x) * 4;
    const float* s;
    if (off < 65536)       s = qw  + off;
    else if (off < 196608) s = kvw + off - 65536;
    else if (off < 262144) s = pw  + off - 196608;
    else if (off < 524288) s = f1  + off - 262144;
    else                   s = f2  + off - 524288;
    float4 v = *(const float4*)s;
    ushort4 u = {f2bf(v.x), f2bf(v.y), f2bf(v.z), f2bf(v.w)};
    *(ushort4*)(wo + off) = u;
    return;
  }
  int t = threadIdx.x;
  int wave = t >> 6, lane = t & 63;
  int j = blockIdx.x - 768;                 // 784 = 8 * 98
  int jj = (j & 7) * 98 + (j >> 3);         // XCD-grouped
  int widx = jj*4 + wave;
  const int nseg = WW/CSEG;                 // 14
  int xseg = widx % nseg;
  int y    = (widx / nseg) % HH;
  int b    = widx / (nseg*HH);
  int c0 = lane*4;
  int x0 = xseg*CSEG;
  float wv[36];
  {
    const float* wp = w + (size_t)c0*9;
#pragma unroll
    for (int i = 0; i < 9; i++){
      float4 v = *(const float4*)(wp + i*4);
      wv[i*4+0]=v.x; wv[i*4+1]=v.y; wv[i*4+2]=v.z; wv[i*4+3]=v.w;
    }
  }
  float4 bi4 = *(const float4*)&bias[c0];
  float bi[4] = {bi4.x, bi4.y, bi4.z, bi4.w};
  float4 gv = *(const float4*)&g[c0];
  float4 bv = *(const float4*)&be[c0];
  const float* rowc = x + ((size_t)b*NN + (size_t)y*WW)*CC + c0;
  const float* rowm = (y > 0)    ? rowc - (size_t)WW*CC : rowc;
  const float* rowp = (y < HH-1) ? rowc + (size_t)WW*CC : rowc;
  if (y == 0){
#pragma unroll
    for (int cc = 0; cc < 4; cc++){ wv[cc*9+0]=0.f; wv[cc*9+1]=0.f; wv[cc*9+2]=0.f; }
  }
  if (y == HH-1){
#pragma unroll
    for (int cc = 0; cc < 4; cc++){ wv[cc*9+6]=0.f; wv[cc*9+7]=0.f; wv[cc*9+8]=0.f; }
  }
  float win[3][3][4];            // [col slot][row][ch]
  float4 rawA[3], rawB[3];
  if (x0 == 0){
#pragma unroll
    for (int r = 0; r < 3; r++)
#pragma unroll
      for (int cc = 0; cc < 4; cc++) win[0][r][cc] = 0.f;
  } else {
    size_t o = (size_t)(x0-1)*CC;
    float4 a0 = *(const float4*)&rowm[o];
    float4 a1 = *(const float4*)&rowc[o];
    float4 a2 = *(const float4*)&rowp[o];
    win[0][0][0]=a0.x; win[0][0][1]=a0.y; win[0][0][2]=a0.z; win[0][0][3]=a0.w;
    win[0][1][0]=a1.x; win[0][1][1]=a1.y; win[0][1][2]=a1.z; win[0][1][3]=a1.w;
    win[0][2][0]=a2.x; win[0][2][1]=a2.y; win[0][2][2]=a2.z; win[0][2][3]=a2.w;
  }
  {
    size_t o = (size_t)x0*CC;
    float4 a0 = *(const float4*)&rowm[o];
    float4 a1 = *(const float4*)&rowc[o];
    float4 a2 = *(const float4*)&rowp[o];
    win[1][0][0]=a0.x; win[1][0][1]=a0.y; win[1][0][2]=a0.z; win[1][0][3]=a0.w;
    win[1][1][0]=a1.x; win[1][1][1]=a1.y; win[1][1][2]=a1.z; win[1][1][3]=a1.w;
    win[1][2][0]=a2.x; win[1][2][1]=a2.y; win[1][2][2]=a2.z; win[1][2][3]=a2.w;
  }
  {
    size_t o = (size_t)(x0+1)*CC;      // x0+1 <= 53 < WW always
    rawA[0] = *(const float4*)&rowm[o];
    rawA[1] = *(const float4*)&rowc[o];
    rawA[2] = *(const float4*)&rowp[o];
  }
#pragma unroll
  for (int xx = 0; xx < CSEG; xx++){
    float4* cur = (xx & 1) ? rawB : rawA;
    float4* nxt = (xx & 1) ? rawA : rawB;
    if (xx < CSEG-1){
      int xg = x0 + xx + 2;
      if (xg < WW){
        size_t o = (size_t)xg*CC;
        nxt[0] = *(const float4*)&rowm[o];
        nxt[1] = *(const float4*)&rowc[o];
        nxt[2] = *(const float4*)&rowp[o];
      } else {
        float4 z = {0.f,0.f,0.f,0.f};
        nxt[0] = z; nxt[1] = z; nxt[2] = z;
      }
    }
    int sl2 = (xx+2)%3, slm = xx%3, slc = (xx+1)%3;
#pragma unroll
    for (int r = 0; r < 3; r++){
      win[sl2][r][0]=cur[r].x; win[sl2][r][1]=cur[r].y;
      win[sl2][r][2]=cur[r].z; win[sl2][r][3]=cur[r].w;
    }
    float o4[4];
#pragma unroll
    for (int cc = 0; cc < 4; cc++){
      float a = bi[cc];
      a += win[slm][0][cc]*wv[cc*9+0] + win[slc][0][cc]*wv[cc*9+1] + win[sl2][0][cc]*wv[cc*9+2];
      a += win[slm][1][cc]*wv[cc*9+3] + win[slc][1][cc]*wv[cc*9+4] + win[sl2][1][cc]*wv[cc*9+5];
      a += win[slm][2][cc]*wv[cc*9+6] + win[slc][2][cc]*wv[cc*9+7] + win[sl2][2][cc]*wv[cc*9+8];
      o4[cc] = win[slc][1][cc] + a;
    }
    size_t pix = (size_t)b*NN + (size_t)y*WW + x0 + xx;
    float4 ov = {o4[0],o4[1],o4[2],o4[3]};
    *(float4*)&x1[pix*CC + c0] = ov;
    float s  = o4[0]+o4[1]+o4[2]+o4[3];
    float s2 = o4[0]*o4[0]+o4[1]*o4[1]+o4[2]*o4[2]+o4[3]*o4[3];
#pragma unroll
    for (int off = 32; off; off >>= 1){
      s  += __shfl_xor(s,  off);
      s2 += __shfl_xor(s2, off);
    }
    float mean = s * (1.f/CC);
    float var  = s2 * (1.f/CC) - mean*mean;
    float rstd = rsqrtf(var + EPS_LN);
    float y0 = (o4[0]-mean)*rstd*gv.x + bv.x;
    float y1 = (o4[1]-mean)*rstd*gv.y + bv.y;
    float y2 = (o4[2]-mean)*rstd*gv.z + bv.z;
    float y3 = (o4[3]-mean)*rstd*gv.w + bv.w;
    ushort4 yb = {f2bf_r(y0), f2bf_r(y1), f2bf_r(y2), f2bf_r(y3)};
    *(ushort4*)&xnb[pix*CC + c0] = yb;
  }
}

// ---------------- LayerNorm f32 -> bf16 ----------------
// R15: one WAVE per row (no LDS, no barriers); lane owns 4 cols via float4.
__global__ void k_ln_bf16(const float* __restrict__ X, const float* __restrict__ g,
                          const float* __restrict__ be, bf16u* __restrict__ Y){
  int wave = threadIdx.x >> 6, lane = threadIdx.x & 63;
  int row = blockIdx.x*4 + wave;
  int c0 = lane*4;
  float4 v = *(const float4*)&X[(size_t)row*CC + c0];
  float s  = v.x+v.y+v.z+v.w;
  float s2 = v.x*v.x+v.y*v.y+v.z*v.z+v.w*v.w;
#pragma unroll
  for (int off = 32; off; off >>= 1){
    s  += __shfl_xor(s,  off);
    s2 += __shfl_xor(s2, off);
  }
  float mean = s * (1.f/CC);
  float var  = s2 * (1.f/CC) - mean*mean;
  float rstd = rsqrtf(var + EPS_LN);
  float4 gv = *(const float4*)&g[c0];
  float4 bv = *(const float4*)&be[c0];
  ushort4 yb = {f2bf_r((v.x-mean)*rstd*gv.x + bv.x),
                f2bf_r((v.y-mean)*rstd*gv.y + bv.y),
                f2bf_r((v.z-mean)*rstd*gv.z + bv.z),
                f2bf_r((v.w-mean)*rstd*gv.w + bv.w)};
  *(ushort4*)&Y[(size_t)row*CC + c0] = yb;
}

// ===== GEMM body (device): Out = act(oscale*(A @ W^T) + bias) (+Res) =====
// R12 pipelined staging; R15 depth-2 register prefetch; R18 relaxed barriers.
// R24: MT=32 REVERTED (R23 neutral-negative: fixed prologue + duplicated A-loads
// offset the occupancy gain). 64x64 is the measured-best tile for all CC-out GEMMs.
#define GST 40
template<int MT, int NT, bool OUT_BF16, bool HAS_BIAS, bool DO_GELU, bool HAS_RES, bool VT_OUT>
__device__ __forceinline__ void gemm_body(int bx, int by,
                       const bf16u* __restrict__ A, const bf16u* __restrict__ Wt,
                       const float* __restrict__ bias, void* Outp,
                       const float* Res, bf16u* __restrict__ vtout,
                       int Nout, int K, float oscale,
                       bf16u* __restrict__ AshB, bf16u* __restrict__ BshB){
  constexpr int MW = (MT == 128) ? 4 : 2;
  constexpr int NW = (NT == 128) ? 4 : 2;
  bf16u* Ash0 = AshB; bf16u* Ash1 = AshB + MT*GST;
  bf16u* Bsh0 = BshB; bf16u* Bsh1 = BshB + NT*GST;
  int t = threadIdx.x;
  int wave = t >> 6, lane = t & 63, quad = lane >> 4, l16 = lane & 15;
  int m0 = by * MT, n0 = bx * NT;
  int wm = (wave >> 1) * (MT/2);
  int wn = (wave & 1) * (NT/2);
  int ar = (MT==128) ? (t>>1) : (t>>2);
  int ac = (MT==128) ? ((t&1)*16) : ((t&3)*8);
  int br = (NT==128) ? (t>>1) : (t>>2);
  int bc = (NT==128) ? ((t&1)*16) : ((t&3)*8);
  int astore = ar*GST + ac;
  int bstore = br*GST + bc;
  const bf16u* ap = A  + (size_t)(m0+ar)*K + ac;
  const bf16u* bp = Wt + (size_t)(n0+br)*K + bc;

  // prologue: stage chunk 0 directly; prefetch chunk 1 -> setA, chunk 2 -> setB
  {
    uint4 t0 = *(const uint4*)ap;
    *(uint4*)&Ash0[astore] = t0;
    if constexpr (MT == 128){ uint4 t1 = *(const uint4*)(ap+8); *(uint4*)&Ash0[astore+8] = t1; }
    uint4 t2 = *(const uint4*)bp;
    *(uint4*)&Bsh0[bstore] = t2;
    if constexpr (NT == 128){ uint4 t3 = *(const uint4*)(bp+8); *(uint4*)&Bsh0[bstore+8] = t3; }
  }
  uint4 aA0, aA1, bA0, bA1;   // setA (odd chunks)
  uint4 aB0, aB1, bB0, bB1;   // setB (even chunks)
  ap += 32; bp += 32;
  aA0 = *(const uint4*)ap;
  if constexpr (MT == 128) aA1 = *(const uint4*)(ap+8);
  bA0 = *(const uint4*)bp;
  if constexpr (NT == 128) bA1 = *(const uint4*)(bp+8);
  ap += 32; bp += 32;
  aB0 = *(const uint4*)ap;
  if constexpr (MT == 128) aB1 = *(const uint4*)(ap+8);
  bB0 = *(const uint4*)bp;
  if constexpr (NT == 128) bB1 = *(const uint4*)(bp+8);
  ap += 32; bp += 32;        // -> chunk 3
  bar_lgkm();

  f32x4 zero = {0.f,0.f,0.f,0.f};
  f32x4 acc[MW][NW];
#pragma unroll
  for (int i = 0; i < MW; i++)
#pragma unroll
    for (int j = 0; j < NW; j++) acc[i][j] = zero;

  int nks = K >> 5;

#define GEMM_STEP(AshP, BshP) { \
    short8 af[MW], bfr[NW]; \
    _Pragma("unroll") \
    for (int mi = 0; mi < MW; mi++) \
      af[mi] = *(const short8*)&AshP[(wm + mi*16 + l16)*GST + quad*8]; \
    _Pragma("unroll") \
    for (int ni = 0; ni < NW; ni++) \
      bfr[ni] = *(const short8*)&BshP[(wn + ni*16 + l16)*GST + quad*8]; \
    _Pragma("unroll") \
    for (int mi = 0; mi < MW; mi++) \
      _Pragma("unroll") \
      for (int ni = 0; ni < NW; ni++) \
        acc[mi][ni] = __builtin_amdgcn_mfma_f32_16x16x32_bf16(af[mi], bfr[ni], acc[mi][ni], 0,0,0); }

  for (int ks = 0; ks < nks; ks += 2){
    // even sub-iter: compute buf0; store setA (chunk ks+1) -> buf1; reload setA <- chunk ks+3
    if (ks < nks-1){
      *(uint4*)&Ash1[astore] = aA0;
      if constexpr (MT == 128) *(uint4*)&Ash1[astore+8] = aA1;
      *(uint4*)&Bsh1[bstore] = bA0;
      if constexpr (NT == 128) *(uint4*)&Bsh1[bstore+8] = bA1;
      if (ks < nks-3){
        aA0 = *(const uint4*)ap;
        if constexpr (MT == 128) aA1 = *(const uint4*)(ap+8);
        bA0 = *(const uint4*)bp;
        if constexpr (NT == 128) bA1 = *(const uint4*)(bp+8);
        ap += 32; bp += 32;
      }
    }
    GEMM_STEP(Ash0, Bsh0)
    if (ks < nks-1) bar_lgkm();
    // odd sub-iter: compute buf1; store setB (chunk ks+2) -> buf0; reload setB <- chunk ks+4
    if (ks+1 < nks-1){
      *(uint4*)&Ash0[astore] = aB0;
      if constexpr (MT == 128) *(uint4*)&Ash0[astore+8] = aB1;
      *(uint4*)&Bsh0[bstore] = bB0;
      if constexpr (NT == 128) *(uint4*)&Bsh0[bstore+8] = bB1;
      if (ks+1 < nks-3){
        aB0 = *(const uint4*)ap;
        if constexpr (MT == 128) aB1 = *(const uint4*)(ap+8);
        bB0 = *(const uint4*)bp;
        if constexpr (NT == 128) bB1 = *(const uint4*)(bp+8);
        ap += 32; bp += 32;
      }
    }
    if (ks+1 < nks){
      GEMM_STEP(Ash1, Bsh1)
      if (ks+1 < nks-1) bar_lgkm();
    }
  }
#undef GEMM_STEP

#pragma unroll
  for (int mi = 0; mi < MW; mi++){
#pragma unroll
    for (int r = 0; r < 4; r++){
      int row = m0 + wm + mi*16 + quad*4 + r;
#pragma unroll
      for (int ni = 0; ni < NW; ni++){
        int col = n0 + wn + ni*16 + l16;
        float v = acc[mi][ni][r] * oscale;
        if constexpr (HAS_BIAS) v += bias[col];
        if constexpr (DO_GELU)  v = 0.5f*v*(1.f + erff(v*0.70710678118654752f));
        if constexpr (HAS_RES)  v += Res[(size_t)row*Nout + col];
        if constexpr (VT_OUT){
          if (col < CC){
            ((bf16u*)Outp)[(size_t)row*Nout + col] = f2bf_r(v);
          } else {
            int bb = row / PP, pp = row - bb*PP;
            vtout[((size_t)(bb*CC + (col - CC)))*PPAD + pp] = f2bf_r(v);
          }
        } else if constexpr (OUT_BF16){
          ((bf16u*)Outp)[(size_t)row*Nout + col] = f2bf_r(v);
        } else {
          ((float*)Outp)[(size_t)row*Nout + col] = v;
        }
      }
    }
  }
}

// R18: 1-D grid + bijective XCD swizzle (nwg % 8 == 0 at every call site).
template<int MT, int NT, bool OUT_BF16, bool HAS_BIAS, bool DO_GELU, bool HAS_RES, bool VT_OUT>
__global__ __launch_bounds__(256) void k_gemm_mfma(const bf16u* __restrict__ A,
                       const bf16u* __restrict__ Wt,
                       const float* __restrict__ bias, void* Outp,
                       const float* Res, bf16u* __restrict__ vtout,
                       int NX, int Nout, int K, float oscale){
  __shared__ bf16u Ash[2][MT*GST];
  __shared__ bf16u Bsh[2][NT*GST];
  int i = blockIdx.x;
  int w = (i & 7) * ((int)gridDim.x >> 3) + (i >> 3);
  int bx = w % NX, by = w / NX;
  gemm_body<MT,NT,OUT_BF16,HAS_BIAS,DO_GELU,HAS_RES,VT_OUT>(
      bx, by, A, Wt, bias, Outp, Res, vtout, Nout, K, oscale,
      &Ash[0][0], &Bsh[0][0]);
}

// ---------------- R17 fused: q-projection GEMM + adaptive avg pool ----------------
#define QGRID ((CC/64)*(BQ*NN/64))    // 4*196 = 784
__global__ __launch_bounds__(256) void k_qpool(const bf16u* __restrict__ xnb,
                       const bf16u* __restrict__ wq, bf16u* __restrict__ qb,
                       float* __restrict__ praw){
  __shared__ bf16u Ash[2][64*GST];
  __shared__ bf16u Bsh[2][64*GST];
  if (blockIdx.x < QGRID){
    int i = blockIdx.x;
    int w = (i & 7) * (QGRID >> 3) + (i >> 3);   // XCD swizzle within q part
    int bx = w & 3, by = w >> 2;
    gemm_body<64,64,true,false,false,false,false>(
        bx, by, xnb, wq, nullptr, qb, nullptr, nullptr, CC, CC, QSCALE_LOG2E,
        &Ash[0][0], &Bsh[0][0]);
    return;
  }
  // pool path: one wave per pool pixel, lane owns 4 channels
  int wave = threadIdx.x >> 6, lane = threadIdx.x & 63;
  int bp = (blockIdx.x - QGRID)*4 + wave;
  int b = bp / PP, p = bp % PP;
  int ps, pi;
  if (p < 144)      { ps = 12; pi = p; }
  else if (p < 400) { ps = 16; pi = p - 144; }
  else if (p < 800) { ps = 20; pi = p - 400; }
  else              { ps = 24; pi = p - 800; }
  int oi = pi / ps, oj = pi % ps;
  int si = oi*HH/ps, ei = ((oi+1)*HH + ps - 1)/ps;
  int sj = oj*WW/ps, ej = ((oj+1)*WW + ps - 1)/ps;
  int c0 = lane*4;
  const bf16u* xb = xnb + (size_t)b*NN*CC + c0;
  float a0=0.f, a1=0.f, a2=0.f, a3=0.f;
  for (int i = si; i < ei; i++)
    for (int j = sj; j < ej; j++){
      ushort4 v = *(const ushort4*)&xb[(size_t)(i*WW+j)*CC];
      a0 += bf2f(v.x); a1 += bf2f(v.y); a2 += bf2f(v.z); a3 += bf2f(v.w);
    }
  float inv = 1.f / (float)((ei-si)*(ej-sj));
  float4 o = {a0*inv, a1*inv, a2*inv, a3*inv};
  *(float4*)&praw[(size_t)bp*CC + c0] = o;
}

// ---------------- pool-dwconv + attn-norm fused -> bf16 ----------------
// R21: one WAVE per pool pixel (4/block), lane owns 4 channels via float4.
__global__ __launch_bounds__(256) void k_pooldw_ln(const float* __restrict__ praw,
    const float* w0, const float* b0, const float* w1, const float* b1,
    const float* w2, const float* b2, const float* w3, const float* b3,
    const float* __restrict__ g, const float* __restrict__ be,
    bf16u* __restrict__ pools){
  int wave = threadIdx.x >> 6, lane = threadIdx.x & 63;
  int bp = blockIdx.x*4 + wave;
  int b = bp / PP, p = bp % PP;
  int ps, pi, off; const float *w, *bi;
  if (p < 144)      { ps=12; pi=p;     off=0;   w=w0; bi=b0; }
  else if (p < 400) { ps=16; pi=p-144; off=144; w=w1; bi=b1; }
  else if (p < 800) { ps=20; pi=p-400; off=400; w=w2; bi=b2; }
  else              { ps=24; pi=p-800; off=800; w=w3; bi=b3; }
  int oi = pi/ps, oj = pi%ps;
  int c0 = lane*4;
  const float* base = praw + (size_t)(b*PP + off)*CC + c0;
  // weights for 4 channels (dwconv layout [C][9] -> per-channel scalar loads)
  float wv[36];
#pragma unroll
  for (int cc = 0; cc < 4; cc++)
#pragma unroll
    for (int k = 0; k < 9; k++) wv[cc*9+k] = w[(size_t)(c0+cc)*9 + k];
  float4 bi4 = *(const float4*)&bi[c0];
  float acc[4] = {bi4.x, bi4.y, bi4.z, bi4.w};
#pragma unroll
  for (int kh = 0; kh < 3; kh++){
    int ii = oi + kh - 1; if (ii < 0 || ii >= ps) continue;
#pragma unroll
    for (int kw = 0; kw < 3; kw++){
      int jj = oj + kw - 1; if (jj < 0 || jj >= ps) continue;
      float4 v = *(const float4*)&base[(size_t)(ii*ps+jj)*CC];
      int k = kh*3+kw;
      acc[0] += v.x*wv[0*9+k]; acc[1] += v.y*wv[1*9+k];
      acc[2] += v.z*wv[2*9+k]; acc[3] += v.w*wv[3*9+k];
    }
  }
  float4 ctr = *(const float4*)&base[(size_t)(oi*ps+oj)*CC];
  float v0 = ctr.x + acc[0], v1 = ctr.y + acc[1];
  float v2 = ctr.z + acc[2], v3 = ctr.w + acc[3];
  float s  = v0+v1+v2+v3;
  float s2 = v0*v0+v1*v1+v2*v2+v3*v3;
#pragma unroll
  for (int o2_ = 32; o2_; o2_ >>= 1){
    s  += __shfl_xor(s,  o2_);
    s2 += __shfl_xor(s2, o2_);
  }
  float mean = s * (1.f/CC);
  float var  = s2 * (1.f/CC) - mean*mean;
  float rstd = rsqrtf(var + EPS_LN);
  float4 gv = *(const float4*)&g[c0];
  float4 bv = *(const float4*)&be[c0];
  ushort4 yb = {f2bf_r((v0-mean)*rstd*gv.x + bv.x),
                f2bf_r((v1-mean)*rstd*gv.y + bv.y),
                f2bf_r((v2-mean)*rstd*gv.z + bv.z),
                f2bf_r((v3-mean)*rstd*gv.w + bv.w)};
  *(ushort4*)&pools[(size_t)bp*CC + c0] = yb;
}

// ============ MFMA flash attention: 64 q x 1 head per block, 64-key chunks ============
// R14 layout (sigma store permute, linear frag reads, KST=40). R15 VALU cuts
// (ones-MFMA rowsum, perm-pack). R18 relaxed barriers + XCD grouping.
// R19: DEPTH-2 K/V register prefetch (statically 2x-unrolled chunk loop).
#define KST 40   // 32 dims + 8 pad
#define VST 72   // 64 keys + 8 pad
__global__ __launch_bounds__(256) void k_attn_mfma(const bf16u* __restrict__ q,
                       const bf16u* __restrict__ kvb, const bf16u* __restrict__ vt,
                       bf16u* __restrict__ out){
  __shared__ bf16u Ksh[2][64*KST];     // [buf][sigma(key)][32 dims]
  __shared__ bf16u Vsh[2][32*VST];     // [buf][d][64 keys]
  int t = threadIdx.x;
  int wave = t >> 6, lane = t & 63, quad = lane >> 4, l16 = lane & 15;
  int i = blockIdx.x;                      // 1568 = 8 * 196
  int bid = (i & 7) * 196 + (i >> 3);      // 49-block (b,h) groups stay on one XCD
  int qt = bid % (NN/64);
  int h  = (bid / (NN/64)) % NHEAD;
  int b  = bid / ((NN/64)*NHEAD);
  int q0 = qt*64 + wave*16;
  const bf16u* qptr = q + (size_t)(b*NN + q0 + l16)*CC + h*HD + quad*8;
  short8 qf = *(const short8*)qptr;
  f32x4 zero = {0.f,0.f,0.f,0.f};
  f32x4 o0 = zero, o1 = zero, osum = zero;
  const short8 onesf = {0x3F80,0x3F80,0x3F80,0x3F80,0x3F80,0x3F80,0x3F80,0x3F80};
  // staging: K chunk = 64 rows x 64B (4 thr/row), V chunk = 32 rows x 128B (8 thr/row)
  int ksr = t >> 2, ksc = (t & 3) * 8;
  int vsr = t >> 3, vsc = (t & 7) * 8;
  const bf16u* ksrc = kvb + (size_t)(b*PP + ksr)*(2*CC) + h*HD + ksc;
  const bf16u* vsrc = vt  + (size_t)(b*CC + h*HD + vsr)*PPAD + vsc;
  const size_t KSTEP = (size_t)64*(2*CC);
  // sigma(key): bit5=k5, bit4=k2, bits3:2=k4:3, bits1:0=k1:0 (pure bit permutation)
  int krow = (ksr & 32) | ((ksr & 4) << 2) | ((ksr & 24) >> 1) | (ksr & 3);
  int kstore = krow*KST + ksc;
  int vstore = vsr*VST + vsc;
  // linear fragment reads (conflict-free at stride 40)
  int koffA = l16*KST + quad*8;
  int koffB = koffA + 16*KST;
  int voff0 = l16*VST + quad*8;
  int voff1 = (16 + l16)*VST + quad*8;
  bf16u* Ksh0 = &Ksh[0][0]; bf16u* Ksh1 = &Ksh[1][0];
  bf16u* Vsh0 = &Vsh[0][0]; bf16u* Vsh1 = &Vsh[1][0];

  // prologue: stage chunk 0 -> buf0; load chunk 1 -> setA; chunk 2 -> setB
  {
    uint4 k0 = *(const uint4*)ksrc;
    uint4 v0 = *(const uint4*)vsrc;
    *(uint4*)&Ksh0[kstore] = k0;
    *(uint4*)&Vsh0[vstore] = v0;
  }
  uint4 kA, vA, kB, vB;
  ksrc += KSTEP; vsrc += 64;
  kA = *(const uint4*)ksrc; vA = *(const uint4*)vsrc;
  ksrc += KSTEP; vsrc += 64;
  kB = *(const uint4*)ksrc; vB = *(const uint4*)vsrc;
  ksrc += KSTEP; vsrc += 64;       // -> chunk 3
  bar_lgkm();

#define PAIR(KB_, VB_, cb) { \
    short8 kfa = *(const short8*)&KB_[cb*KST + koffA]; \
    short8 kfb = *(const short8*)&KB_[cb*KST + koffB]; \
    f32x4 sa = __builtin_amdgcn_mfma_f32_16x16x32_bf16(kfa, qf, zero, 0,0,0); \
    f32x4 sb = __builtin_amdgcn_mfma_f32_16x16x32_bf16(kfb, qf, zero, 0,0,0); \
    float ea0 = __builtin_amdgcn_exp2f(sa[0]), ea1 = __builtin_amdgcn_exp2f(sa[1]); \
    float ea2 = __builtin_amdgcn_exp2f(sa[2]), ea3 = __builtin_amdgcn_exp2f(sa[3]); \
    float eb0 = __builtin_amdgcn_exp2f(sb[0]), eb1 = __builtin_amdgcn_exp2f(sb[1]); \
    float eb2 = __builtin_amdgcn_exp2f(sb[2]), eb3 = __builtin_amdgcn_exp2f(sb[3]); \
    unsigned ra0 = __float_as_uint(ea0) + 0x8000u, ra1 = __float_as_uint(ea1) + 0x8000u; \
    unsigned ra2 = __float_as_uint(ea2) + 0x8000u, ra3 = __float_as_uint(ea3) + 0x8000u; \
    unsigned rb0 = __float_as_uint(eb0) + 0x8000u, rb1 = __float_as_uint(eb1) + 0x8000u; \
    unsigned rb2 = __float_as_uint(eb2) + 0x8000u, rb3 = __float_as_uint(eb3) + 0x8000u; \
    union { uint4 u; short8 s; } pk; \
    pk.u.x = __builtin_amdgcn_perm(ra1, ra0, 0x07060302u); \
    pk.u.y = __builtin_amdgcn_perm(ra3, ra2, 0x07060302u); \
    pk.u.z = __builtin_amdgcn_perm(rb1, rb0, 0x07060302u); \
    pk.u.w = __builtin_amdgcn_perm(rb3, rb2, 0x07060302u); \
    short8 pa = pk.s; \
    short8 vf0 = *(const short8*)&VB_[cb + voff0]; \
    short8 vf1 = *(const short8*)&VB_[cb + voff1]; \
    o0 = __builtin_amdgcn_mfma_f32_16x16x32_bf16(pa, vf0, o0, 0,0,0); \
    o1 = __builtin_amdgcn_mfma_f32_16x16x32_bf16(pa, vf1, o1, 0,0,0); \
    osum = __builtin_amdgcn_mfma_f32_16x16x32_bf16(pa, onesf, osum, 0,0,0); }

  // chunks 0..20 processed in iters 0..20; chunk c lives in buf c&1.
  for (int ch = 0; ch < 20; ch += 2){
    // even iter ch: read buf0, store setA (chunk ch+1) -> buf1
    *(uint4*)&Ksh1[kstore] = kA;
    *(uint4*)&Vsh1[vstore] = vA;
    kA = *(const uint4*)ksrc; vA = *(const uint4*)vsrc;   // chunk ch+3
    ksrc += KSTEP; vsrc += 64;
    PAIR(Ksh0, Vsh0, 0)
    PAIR(Ksh0, Vsh0, 32)
    bar_lgkm();
    // odd iter ch+1: read buf1, store setB (chunk ch+2) -> buf0
    *(uint4*)&Ksh0[kstore] = kB;
    *(uint4*)&Vsh0[vstore] = vB;
    if (ch+1 <= 17){                                      // chunk ch+4 valid (<=21)
      kB = *(const uint4*)ksrc; vB = *(const uint4*)vsrc;
      ksrc += KSTEP; vsrc += 64;
    }
    PAIR(Ksh1, Vsh1, 0)
    PAIR(Ksh1, Vsh1, 32)
    bar_lgkm();
  }
  // iter 20 (even): store setA (chunk 21) -> buf1; no further loads
  *(uint4*)&Ksh1[kstore] = kA;
  *(uint4*)&Vsh1[vstore] = vA;
  PAIR(Ksh0, Vsh0, 0)
  PAIR(Ksh0, Vsh0, 32)
  bar_lgkm();
  // tail chunk 21 (buf1): keys 1344..1375 valid, 1376..1407 masked off entirely
  PAIR(Ksh1, Vsh1, 0)
#undef PAIR

  // osum[r] = sum of P over all keys for q-row quad*4+r -- exactly the row this
  // lane writes; no shuffles needed.
#pragma unroll
  for (int r = 0; r < 4; r++){
    int qq = quad*4 + r;
    float inv = 1.f / osum[r];
    size_t base = (size_t)(b*NN + q0 + qq)*CC + h*HD;
    out[base + l16]      = f2bf_r(o0[r]*inv);
    out[base + 16 + l16] = f2bf_r(o1[r]*inv);
  }
}

// ---------------- h2 = h + dwconv3x3(h) + bias (hid=1024, bf16) ----------------
// R11: sliding-window row kernel. R22: XCD-grouped bid (1568 = 8*196) so blocks
// sharing y+-1 halo rows of hbuf hit one L2.
#define DWSEG 8
__global__ __launch_bounds__(256) void k_dwh(const bf16u* __restrict__ h, const float* __restrict__ w,
                      const float* __restrict__ bias, bf16u* __restrict__ h2){
  const int nseg = WW/DWSEG;     // 7
  int i = blockIdx.x;            // 1568 = 8 * 196
  int bid = (i & 7) * 196 + (i >> 3);
  int xseg = bid % nseg;
  int y    = (bid / nseg) % HH;
  int b    = bid / (nseg*HH);
  int t = threadIdx.x;
  int c0 = t*4;
  int x0 = xseg*DWSEG;
  float wv[36];
  {
    const float4* wp = (const float4*)(w + (size_t)c0*9);
#pragma unroll
    for (int i2 = 0; i2 < 9; i2++){
      float4 v = wp[i2];
      wv[i2*4+0]=v.x; wv[i2*4+1]=v.y; wv[i2*4+2]=v.z; wv[i2*4+3]=v.w;
    }
  }
  float4 bi4 = *(const float4*)&bias[c0];
  float bi[4] = {bi4.x, bi4.y, bi4.z, bi4.w};
  const bf16u* rowc = h + ((size_t)b*NN + (size_t)y*WW)*HIDN + c0;
  const bf16u* rowm = (y > 0)    ? rowc - (size_t)WW*HIDN : rowc;
  const bf16u* rowp = (y < HH-1) ? rowc + (size_t)WW*HIDN : rowc;
  if (y == 0){
#pragma unroll
    for (int cc = 0; cc < 4; cc++){ wv[cc*9+0]=0.f; wv[cc*9+1]=0.f; wv[cc*9+2]=0.f; }
  }
  if (y == HH-1){
#pragma unroll
    for (int cc = 0; cc < 4; cc++){ wv[cc*9+6]=0.f; wv[cc*9+7]=0.f; wv[cc*9+8]=0.f; }
  }
  float win[3][3][4];            // [col slot][row][ch]
  ushort4 rawA[3], rawB[3];
  if (x0 == 0){
#pragma unroll
    for (int r = 0; r < 3; r++)
#pragma unroll
      for (int cc = 0; cc < 4; cc++) win[0][r][cc] = 0.f;
  } else {
    size_t o = (size_t)(x0-1)*HIDN;
    ushort4 a0 = *(const ushort4*)&rowm[o];
    ushort4 a1 = *(const ushort4*)&rowc[o];
    ushort4 a2 = *(const ushort4*)&rowp[o];
    cvt4(a0, win[0][0]); cvt4(a1, win[0][1]); cvt4(a2, win[0][2]);
  }
  {
    size_t o = (size_t)x0*HIDN;
    ushort4 a0 = *(const ushort4*)&rowm[o];
    ushort4 a1 = *(const ushort4*)&rowc[o];
    ushort4 a2 = *(const ushort4*)&rowp[o];
    cvt4(a0, win[1][0]); cvt4(a1, win[1][1]); cvt4(a2, win[1][2]);
  }
  {
    size_t o = (size_t)(x0+1)*HIDN;
    rawA[0] = *(const ushort4*)&rowm[o];
    rawA[1] = *(const ushort4*)&rowc[o];
    rawA[2] = *(const ushort4*)&rowp[o];
  }
#pragma unroll
  for (int x = 0; x < DWSEG; x++){
    ushort4* cur = (x & 1) ? rawB : rawA;
    ushort4* nxt = (x & 1) ? rawA : rawB;
    if (x < DWSEG-1){
      int xg = x0 + x + 2;
      if (xg < WW){
        size_t o = (size_t)xg*HIDN;
        nxt[0] = *(const ushort4*)&rowm[o];
        nxt[1] = *(const ushort4*)&rowc[o];
        nxt[2] = *(const ushort4*)&rowp[o];
      } else {
        ushort4 z = {0,0,0,0};
        nxt[0] = z; nxt[1] = z; nxt[2] = z;
      }
    }
    int s2 = (x+2)%3, sm = x%3, sc_ = (x+1)%3;
    cvt4(cur[0], win[s2][0]); cvt4(cur[1], win[s2][1]); cvt4(cur[2], win[s2][2]);
    float o0[4];
#pragma unroll
    for (int cc = 0; cc < 4; cc++){
      float a = bi[cc];
      a += win[sm][0][cc]*wv[cc*9+0] + win[sc_][0][cc]*wv[cc*9+1] + win[s2][0][cc]*wv[cc*9+2];
      a += win[sm][1][cc]*wv[cc*9+3] + win[sc_][1][cc]*wv[cc*9+4] + win[s2][1][cc]*wv[cc*9+5];
      a += win[sm][2][cc]*wv[cc*9+6] + win[sc_][2][cc]*wv[cc*9+7] + win[s2][2][cc]*wv[cc*9+8];
      o0[cc] = win[sc_][1][cc] + a;
    }
    ushort4 ou = {f2bf_r(o0[0]), f2bf_r(o0[1]), f2bf_r(o0[2]), f2bf_r(o0[3])};
    *(ushort4*)&h2[((size_t)b*NN + (size_t)y*WW + x0 + x)*HIDN + c0] = ou;
  }
}

extern "C" void kernel_launch(void* const* d_in, const int* in_sizes, int n_in,
                              void* d_out, int out_size, void* d_ws, size_t ws_size,
                              hipStream_t stream){
  const float* x      = (const float*)d_in[0];
  const float* cpe_w  = (const float*)d_in[1];
  const float* cpe_b  = (const float*)d_in[2];
  const float* n1w    = (const float*)d_in[3];
  const float* n1b    = (const float*)d_in[4];
  const float* q_w    = (const float*)d_in[5];
  const float* kv_w   = (const float*)d_in[6];
  const float* anw    = (const float*)d_in[7];
  const float* anb    = (const float*)d_in[8];
  const float* proj_w = (const float*)d_in[9];
  const float* proj_b = (const float*)d_in[10];
  const float* n2w    = (const float*)d_in[11];
  const float* n2b    = (const float*)d_in[12];
  const float* fc1_w  = (const float*)d_in[13];
  const float* fc1_b  = (const float*)d_in[14];
  const float* irb_w  = (const float*)d_in[15];
  const float* irb_b  = (const float*)d_in[16];
  const float* fc2_w  = (const float*)d_in[17];
  const float* fc2_b  = (const float*)d_in[18];
  const float* dw0    = (const float*)d_in[21];
  const float* db0    = (const float*)d_in[22];
  const float* dw1    = (const float*)d_in[23];
  const float* db1    = (const float*)d_in[24];
  const float* dw2    = (const float*)d_in[25];
  const float* db2    = (const float*)d_in[26];
  const float* dw3    = (const float*)d_in[27];
  const float* db3    = (const float*)d_in[28];

  const size_t BNC = (size_t)BQ*NN*CC;
  const size_t BPC = (size_t)BQ*PP*CC;
  const size_t BNH = (size_t)BQ*NN*HIDN;

  float* x1   = (float*)d_ws;
  bf16u* xnb  = (bf16u*)(x1 + BNC);
  bf16u* wbuf = xnb + BNC;
  bf16u* wq   = wbuf;
  bf16u* wkv  = wbuf + 65536;
  bf16u* wpj  = wbuf + 196608;
  bf16u* wf1  = wbuf + 262144;
  bf16u* wf2  = wbuf + 524288;
  float* A0   = (float*)(wbuf + 786432);
  bf16u* qb   = (bf16u*)A0;
  float* praw = (float*)(qb + BNC);
  bf16u* poolsb = (bf16u*)(praw + BPC);
  bf16u* kvb  = poolsb + BPC;                 // [BQ*PP][512] (V-half unused by attn)
  bf16u* vtb  = kvb + (size_t)BQ*PP*2*CC;     // [BQ*256][PPAD]
  bf16u* hbuf = (bf16u*)A0;                   // phase-2 overlay (qb dead after proj)
  bf16u* h2buf = hbuf + BNH;

  // 1. weights->bf16 (768 blocks) + CPE+residual+norm1 (784 blocks, XCD-grouped)
  k_init<<<768 + (BQ*HH*(WW/CSEG))/4, 256, 0, stream>>>(q_w, kv_w, proj_w, fc1_w, fc2_w, wbuf,
                                            x, cpe_w, cpe_b, n1w, n1b, x1, xnb);
  // 2+3. fused q projection (784 blocks, XCD-swizzled) + pyramid pooling (1376 blocks)
  k_qpool<<<QGRID + BQ*PP/4, 256, 0, stream>>>(xnb, wq, qb, praw);
  // 4. pool dwconv + attn-norm -> bf16 (1 wave/pixel, float4)
  k_pooldw_ln<<<BQ*PP/4, 256, 0, stream>>>(praw, dw0,db0, dw1,db1, dw2,db2, dw3,db3,
                                           anw, anb, poolsb);
  // 5. kv projection -> bf16, 64x64 tiles (688 blocks, NX=8); V-half -> vtb
  k_gemm_mfma<64,64,true,false,false,false,true><<<(2*CC/64)*(BQ*PP/64), 256, 0, stream>>>(
      poolsb, wkv, nullptr, kvb, nullptr, vtb, 2*CC/64, 2*CC, CC, 1.0f);
  // 6. MFMA attention (in-place: qb becomes attn output); depth-2 prefetch
  k_attn_mfma<<<BQ*NHEAD*(NN/64), 256, 0, stream>>>(qb, kvb, vtb, qb);
  // 7. proj + bias + residual -> x1, R24: back to 64x64 tiles (784 blocks, NX=4)
  k_gemm_mfma<64,64,false,true,false,true,false><<<(CC/64)*(BQ*NN/64), 256, 0, stream>>>(
      qb, wpj, proj_b, x1, x1, nullptr, CC/64, CC, CC, 1.0f);
  // 8. norm2 -> bf16 (1 wave/row)
  k_ln_bf16<<<BQ*NN/4, 256, 0, stream>>>(x1, n2w, n2b, xnb);
  // 9. fc1 + bias + gelu -> hbuf (bf16), 64x64 tiles (3136 blocks, NX=16)
  k_gemm_mfma<64,64,true,true,true,false,false><<<(HIDN/64)*(BQ*NN/64), 256, 0, stream>>>(
      xnb, wf1, fc1_b, hbuf, nullptr, nullptr, HIDN/64, HIDN, CC, 1.0f);
  // 10. h2 = h + dwconv(h), sliding-window row kernel (XCD-grouped)
  k_dwh<<<BQ*HH*(WW/DWSEG), 256, 0, stream>>>(hbuf, irb_w, irb_b, h2buf);
  // 11. fc2 + bias + residual -> d_out (f32), R24: back to 64x64 tiles (784 blocks, NX=4)
  k_gemm_mfma<64,64,false,true,false,true,false><<<(CC/64)*(BQ*NN/64), 256, 0, stream>>>(
      h2buf, wf2, fc2_b, d_out, x1, nullptr, CC/64, CC, HIDN, 1.0f);
}